// Round 5
// baseline (16754.239 us; speedup 1.0000x reference)
//
#include <hip/hip_runtime.h>

#define DD   1024
#define FF   4096
#define NTOK 8192
#define CAPC 4096

__device__ __forceinline__ float block_sum(float v, float* sh){
  #pragma unroll
  for (int off = 32; off > 0; off >>= 1) v += __shfl_down(v, off, 64);
  if ((threadIdx.x & 63) == 0) sh[threadIdx.x >> 6] = v;
  __syncthreads();
  float r = (sh[0] + sh[1]) + (sh[2] + sh[3]);
  __syncthreads();
  return r;
}
__device__ __forceinline__ float block_max(float v, float* sh){
  #pragma unroll
  for (int off = 32; off > 0; off >>= 1) v = fmaxf(v, __shfl_down(v, off, 64));
  if ((threadIdx.x & 63) == 0) sh[threadIdx.x >> 6] = v;
  __syncthreads();
  float r = fmaxf(fmaxf(sh[0], sh[1]), fmaxf(sh[2], sh[3]));
  __syncthreads();
  return r;
}

// 64x64 fp32 tile GEMM core. 256 threads = 16x16, each computes 4x4.
// LOADA sees r_ (tile row), k_ (global k); LOADB sees c_ (tile col), k_.
#define GEMM_CORE(KTILES, LOADA, LOADB) \
  __shared__ float As[64][17]; \
  __shared__ float Bs[16][65]; \
  float cc_[4][4] = {{0,0,0,0},{0,0,0,0},{0,0,0,0},{0,0,0,0}}; \
  const int tx = threadIdx.x & 15, ty = threadIdx.x >> 4; \
  for (int kt = 0; kt < (KTILES); ++kt){ \
    _Pragma("unroll") \
    for (int q_ = 0; q_ < 4; ++q_){ \
      int id_ = q_ * 256 + threadIdx.x; \
      { int r_ = id_ >> 4; int k_ = kt * 16 + (id_ & 15); As[r_][id_ & 15] = (LOADA); } \
      { int c_ = id_ & 63; int k_ = kt * 16 + (id_ >> 6); Bs[id_ >> 6][c_] = (LOADB); } \
    } \
    __syncthreads(); \
    _Pragma("unroll") \
    for (int kk_ = 0; kk_ < 16; ++kk_){ \
      float a_[4], b_[4]; \
      _Pragma("unroll") \
      for (int i_ = 0; i_ < 4; ++i_) a_[i_] = As[ty * 4 + i_][kk_]; \
      _Pragma("unroll") \
      for (int j_ = 0; j_ < 4; ++j_) b_[j_] = Bs[kk_][tx * 4 + j_]; \
      _Pragma("unroll") \
      for (int i_ = 0; i_ < 4; ++i_) \
        _Pragma("unroll") \
        for (int j_ = 0; j_ < 4; ++j_) cc_[i_][j_] += a_[i_] * b_[j_]; \
    } \
    __syncthreads(); \
  }

__device__ __forceinline__ float ln_elem(const float* __restrict__ x, const float* __restrict__ st,
    const float* __restrict__ g, const float* __restrict__ be, int t, int k){
  return (x[(size_t)t * DD + k] - st[2 * t]) * st[2 * t + 1] * g[k] + be[k];
}

// per-token mean/rstd of fp32 rows
__global__ __launch_bounds__(256) void ln_stats(const float* __restrict__ xb, float* __restrict__ stats)
{
  __shared__ float sh[4];
  int n = blockIdx.x, tid = threadIdx.x;
  float4 xv = *(const float4*)(xb + (size_t)n * DD + tid * 4);
  float v[4] = { xv.x, xv.y, xv.z, xv.w };
  float s = (v[0] + v[1]) + (v[2] + v[3]);
  s = block_sum(s, sh);
  float m = s * (1.0f / DD);
  float q = 0;
  #pragma unroll
  for (int i = 0; i < 4; ++i){ float d = v[i] - m; q += d * d; }
  q = block_sum(q, sh);
  if (tid == 0){
    stats[2 * n]     = m;
    stats[2 * n + 1] = 1.0f / sqrtf(q * (1.0f / DD) + 1e-5f);
  }
}

// x1f = x + bo (residual base; per-head O-projection accumulates onto this)
__global__ __launch_bounds__(256) void init_x1(const float* __restrict__ x,
    const float* __restrict__ bo, float* __restrict__ x1f)
{
  size_t i = (size_t)blockIdx.x * 1024 + threadIdx.x * 4;
  float4 xv = *(const float4*)(x + i);
  float4 bv = *(const float4*)(bo + (i & (DD - 1)));
  xv.x += bv.x; xv.y += bv.y; xv.z += bv.z; xv.w += bv.w;
  *(float4*)(x1f + i) = xv;
}

// Q/K/V projection, one head slice: M=8192 tokens, N=64 (cols nofs..nofs+63), K=1024.
// A = LN1(x) on the fly. out[b][s][64] = (acc + bias)*escale.
__global__ __launch_bounds__(256) void proj_gemm(const float* __restrict__ xin,
    const float* __restrict__ st, const float* __restrict__ g, const float* __restrict__ be,
    const float* __restrict__ w, const float* __restrict__ bias, float escale, int nofs,
    float* __restrict__ outq)
{
  const int n0 = blockIdx.x * 64, m0 = blockIdx.y * 64;
  GEMM_CORE(64,
    (ln_elem(xin, st, g, be, m0 + r_, k_)),
    (w[(size_t)k_ * DD + nofs + n0 + c_]))
  #pragma unroll
  for (int i = 0; i < 4; ++i){
    int t = m0 + ty * 4 + i, s = t >> 3, b = t & 7;
    #pragma unroll
    for (int j = 0; j < 4; ++j){
      int col = n0 + tx * 4 + j;
      outq[(size_t)b * 65536 + (size_t)s * 64 + col] = (cc_[i][j] + bias[nofs + col]) * escale;
    }
  }
}

// scores[pz][q][kk] = sum_hd qc[b][q][hd]*kc[b][kk][hd]; M=N=1024, K=64 (NT)
__global__ __launch_bounds__(256) void score_gemm(const float* __restrict__ qc,
    const float* __restrict__ kc, float* __restrict__ sc, int pl0)
{
  const int n0 = blockIdx.x * 64, m0 = blockIdx.y * 64, pz = blockIdx.z;
  const size_t pb = (size_t)(pl0 + pz) * 65536;
  GEMM_CORE(4,
    (qc[pb + (size_t)(m0 + r_) * 64 + k_]),
    (kc[pb + (size_t)(n0 + c_) * 64 + k_]))
  #pragma unroll
  for (int i = 0; i < 4; ++i){
    int row = m0 + ty * 4 + i;
    #pragma unroll
    for (int j = 0; j < 4; ++j)
      sc[(size_t)pz * 1048576 + (size_t)row * 1024 + n0 + tx * 4 + j] = cc_[i][j];
  }
}

// in-place softmax over rows of sc (+causal mask by q = row & 1023)
__global__ __launch_bounds__(256) void softmax_io(float* __restrict__ sc, const float* __restrict__ mask)
{
  __shared__ float sh[4];
  int row = blockIdx.x, tid = threadIdx.x;
  int q = row & 1023;
  float* srow = sc + (size_t)row * 1024;
  const float* mrow = mask + (size_t)q * 1024;
  int j0 = tid * 4;
  float4 sv = *(const float4*)(srow + j0);
  float4 mv = *(const float4*)(mrow + j0);
  float v[4] = { sv.x + mv.x, sv.y + mv.y, sv.z + mv.z, sv.w + mv.w };
  float mx = fmaxf(fmaxf(v[0], v[1]), fmaxf(v[2], v[3]));
  mx = block_max(mx, sh);
  float e[4]; float l = 0;
  #pragma unroll
  for (int i = 0; i < 4; ++i){ e[i] = expf(v[i] - mx); l += e[i]; }
  l = block_sum(l, sh);
  float inv = 1.0f / l;
  #pragma unroll
  for (int i = 0; i < 4; ++i) srow[j0 + i] = e[i] * inv;
}

// o_h[b][s][hd] = sum_kk p[q=s][kk]*vc[b][kk][hd]; M=1024, N=64, K=1024 (NN)
__global__ __launch_bounds__(256) void pv_gemm(const float* __restrict__ sc,
    const float* __restrict__ vc, float* __restrict__ o_h, int pl0)
{
  const int n0 = blockIdx.x * 64, m0 = blockIdx.y * 64, pz = blockIdx.z;
  const size_t pb = (size_t)(pl0 + pz) * 65536;
  GEMM_CORE(64,
    (sc[(size_t)pz * 1048576 + (size_t)(m0 + r_) * 1024 + k_]),
    (vc[pb + (size_t)k_ * 64 + n0 + c_]))
  int b = pl0 + pz;
  #pragma unroll
  for (int i = 0; i < 4; ++i){
    int s = m0 + ty * 4 + i;
    #pragma unroll
    for (int j = 0; j < 4; ++j)
      o_h[(size_t)b * 65536 + (size_t)s * 64 + n0 + tx * 4 + j] = cc_[i][j];
  }
}

// x1f += o_h @ wo[h*64 .. h*64+63][:] ; M=8192, N=1024, K=64
__global__ __launch_bounds__(256) void oproj_acc(const float* __restrict__ o_h,
    const float* __restrict__ wo, int h, float* __restrict__ x1f)
{
  const int n0 = blockIdx.x * 64, m0 = blockIdx.y * 64;
  GEMM_CORE(4,
    (o_h[(size_t)((m0 + r_) & 7) * 65536 + (size_t)((m0 + r_) >> 3) * 64 + k_]),
    (wo[(size_t)(h * 64 + k_) * DD + n0 + c_]))
  #pragma unroll
  for (int i = 0; i < 4; ++i){
    size_t row = m0 + ty * 4 + i;
    #pragma unroll
    for (int j = 0; j < 4; ++j){
      size_t o = row * DD + n0 + tx * 4 + j;
      x1f[o] += cc_[i][j];
    }
  }
}

// gate logits: logits[n][e] = sum_d LN2(x1)[n][d] * gw[d][e]
__global__ __launch_bounds__(256) void logits_gemm(const float* __restrict__ x1f,
    const float* __restrict__ st2, const float* __restrict__ g2, const float* __restrict__ be2,
    const float* __restrict__ gw, float* __restrict__ logits)
{
  int n = blockIdx.x * 4 + (threadIdx.x >> 6);
  int l = threadIdx.x & 63;
  float m = st2[2 * n], rs = st2[2 * n + 1];
  float acc[8] = {0,0,0,0,0,0,0,0};
  for (int i = 0; i < 16; ++i){
    int d = i * 64 + l;
    float t = (x1f[(size_t)n * DD + d] - m) * rs * g2[d] + be2[d];
    const float* gr = gw + (size_t)d * 8;
    #pragma unroll
    for (int e = 0; e < 8; ++e) acc[e] += t * gr[e];
  }
  #pragma unroll
  for (int e = 0; e < 8; ++e){
    #pragma unroll
    for (int off = 32; off > 0; off >>= 1) acc[e] += __shfl_down(acc[e], off, 64);
  }
  if (l == 0){
    #pragma unroll
    for (int e = 0; e < 8; ++e) logits[(size_t)n * 8 + e] = acc[e];
  }
}

__global__ void routing_kernel(const float* __restrict__ logits, float* __restrict__ gval,
    int* __restrict__ src, int* __restrict__ cnt, float* __restrict__ sums)
{
  int n = blockIdx.x * 256 + threadIdx.x;
  if (n >= NTOK) return;
  const float* L = logits + (size_t)n * 8;
  float l[8];
  #pragma unroll
  for (int e = 0; e < 8; ++e) l[e] = L[e];
  float best = l[0]; int be = 0;
  #pragma unroll
  for (int e = 1; e < 8; ++e) if (l[e] > best){ best = l[e]; be = e; }
  float g[8], es = 0;
  #pragma unroll
  for (int e = 0; e < 8; ++e){ g[e] = expf(l[e] - best); es += g[e]; }
  #pragma unroll
  for (int e = 0; e < 8; ++e) atomicAdd(&sums[e], g[e] / es);
  float gv = g[be] / es;
  int r = atomicAdd(&cnt[be], 1);
  bool keep = r < CAPC;
  gval[n] = keep ? gv : 0.0f;
  if (keep) src[be * CAPC + r] = n;
}

__global__ void laux_kernel(const float* __restrict__ sums, const int* __restrict__ cnt,
    float* __restrict__ outp)
{
  if (threadIdx.x == 0 && blockIdx.x == 0){
    float la = 0;
    for (int e = 0; e < 8; ++e) la += (sums[e] * (1.0f / NTOK)) * ((float)cnt[e] * (1.0f / NTOK));
    outp[0] = la * 8.0f;
  }
}

__global__ __launch_bounds__(256) void copy_x1(const float* __restrict__ x1f, float* __restrict__ outp)
{
  size_t i = (size_t)blockIdx.x * 1024 + threadIdx.x * 4;
  *(float4*)(outp + i) = *(const float4*)(x1f + i);
}

// expert GEMM1: h = relu(LN2(x1)[src] @ w1e + b1e); M=1024 chunk, N=4096, K=1024
__global__ __launch_bounds__(256) void moe1_gemm(const float* __restrict__ x1f,
    const float* __restrict__ st2, const float* __restrict__ g2, const float* __restrict__ be2,
    const int* __restrict__ srcp, const int* __restrict__ cntp, int moff,
    const float* __restrict__ w1e, const float* __restrict__ b1e, float* __restrict__ hbuf)
{
  int c = *cntp; if (c > CAPC) c = CAPC; c -= moff; if (c < 0) c = 0;
  const int count = c < 1024 ? c : 1024;
  const int n0 = blockIdx.x * 64, m0 = blockIdx.y * 64;
  if (m0 >= count) return;
  GEMM_CORE(64,
    (ln_elem(x1f, st2, g2, be2, ((m0 + r_) < count ? srcp[m0 + r_] : 0), k_)),
    (w1e[(size_t)k_ * FF + n0 + c_]))
  #pragma unroll
  for (int i = 0; i < 4; ++i){
    int slot = m0 + ty * 4 + i;
    if (slot >= count) continue;
    #pragma unroll
    for (int j = 0; j < 4; ++j){
      int col = n0 + tx * 4 + j;
      hbuf[(size_t)slot * FF + col] = fmaxf(cc_[i][j] + b1e[col], 0.0f);
    }
  }
}

// expert GEMM2 + combine: out[t] += gval[t]*(h@w2e + b2e); M=1024 chunk, N=1024, K=4096
__global__ __launch_bounds__(256) void moe2_gemm(const float* __restrict__ hbuf,
    const float* __restrict__ w2e, const float* __restrict__ b2e, const int* __restrict__ srcp,
    const int* __restrict__ cntp, int moff, const float* __restrict__ gval,
    float* __restrict__ outp)
{
  int c = *cntp; if (c > CAPC) c = CAPC; c -= moff; if (c < 0) c = 0;
  const int count = c < 1024 ? c : 1024;
  const int n0 = blockIdx.x * 64, m0 = blockIdx.y * 64;
  if (m0 >= count) return;
  GEMM_CORE(256,
    (hbuf[(size_t)(m0 + r_) * FF + k_]),
    (w2e[(size_t)k_ * DD + n0 + c_]))
  #pragma unroll
  for (int i = 0; i < 4; ++i){
    int slot = m0 + ty * 4 + i;
    if (slot >= count) continue;
    int t = srcp[slot];
    float gv = gval[t];
    #pragma unroll
    for (int j = 0; j < 4; ++j){
      int col = n0 + tx * 4 + j;
      size_t o = (size_t)t * DD + col;
      outp[o] += gv * (cc_[i][j] + b2e[col]);
    }
  }
}

__global__ void zerofill_kernel(float* o, int nelem){
  int i = blockIdx.x * 256 + threadIdx.x;
  if (i < nelem) o[i] = 0.0f;
}

extern "C" void kernel_launch(void* const* d_in, const int* in_sizes, int n_in,
                              void* d_out, int out_size, void* d_ws, size_t ws_size,
                              hipStream_t stream)
{
  (void)in_sizes; (void)n_in;
  const float* x     = (const float*)d_in[0];
  const float* amask = (const float*)d_in[1];
  const float* wq = (const float*)d_in[2];  const float* bq = (const float*)d_in[3];
  const float* wk = (const float*)d_in[4];  const float* bk = (const float*)d_in[5];
  const float* wv = (const float*)d_in[6];  const float* bv = (const float*)d_in[7];
  const float* wo = (const float*)d_in[8];  const float* bo = (const float*)d_in[9];
  const float* g1 = (const float*)d_in[10]; const float* be1 = (const float*)d_in[11];
  const float* g2 = (const float*)d_in[12]; const float* be2 = (const float*)d_in[13];
  const float* gw = (const float*)d_in[14];
  const float* w1 = (const float*)d_in[15]; const float* b1 = (const float*)d_in[16];
  const float* w2 = (const float*)d_in[17]; const float* b2 = (const float*)d_in[18];
  float* out = (float*)d_out;

  const size_t NEED = 51380224;  // 49.0 MB (ws proven >= 55 MB by rounds 3/4 guards not firing)
  if (ws_size < NEED){
    zerofill_kernel<<<(out_size + 255) / 256, 256, 0, stream>>>(out, out_size);
    return;
  }
  char* W = (char*)d_ws;
  float* gval   = (float*)(W + 0);        // 8192 f
  int*   src    = (int*)  (W + 32768);    // 32768 i
  int*   cnt    = (int*)  (W + 163840);   // 64 i
  float* sums   = (float*)(W + 164096);   // 64 f
  float* stats1 = (float*)(W + 164352);   // 2*8192 f
  float* stats2 = (float*)(W + 229888);   // 2*8192 f
  float* logits = (float*)(W + 295424);   // 8192*8 f
  float* x1f    = (float*)(W + 1048576);  // 32 MB
  char* A = W + 1048576 + 33554432;
  float* qc   = (float*)(A + 0);          // 2 MB [b][s][64]
  float* kc   = (float*)(A + 2097152);    // 2 MB
  float* vc   = (float*)(A + 4194304);    // 2 MB
  float* sc   = (float*)(A + 6291456);    // 8 MB (2-batch score chunk)
  float* o_h  = (float*)(A + 14680064);   // 2 MB [b][s][64]
  float* hbuf = (float*)(A + 0);          // 16 MB (MoE phase, overlays qc..o_h)

  hipMemsetAsync(cnt, 0, 512, stream);  // cnt + sums
  ln_stats<<<NTOK, 256, 0, stream>>>(x, stats1);
  init_x1<<<8192, 256, 0, stream>>>(x, bo, x1f);

  for (int h = 0; h < 16; ++h){
    int nofs = h * 64;
    proj_gemm<<<dim3(1, 128), 256, 0, stream>>>(x, stats1, g1, be1, wq, bq, 0.125f, nofs, qc);
    proj_gemm<<<dim3(1, 128), 256, 0, stream>>>(x, stats1, g1, be1, wk, bk, 1.0f,   nofs, kc);
    proj_gemm<<<dim3(1, 128), 256, 0, stream>>>(x, stats1, g1, be1, wv, bv, 1.0f,   nofs, vc);
    for (int qt = 0; qt < 4; ++qt){  // 8 batches in chunks of 2
      int pl0 = qt * 2;
      score_gemm<<<dim3(16, 16, 2), 256, 0, stream>>>(qc, kc, sc, pl0);
      softmax_io<<<2048, 256, 0, stream>>>(sc, amask);
      pv_gemm<<<dim3(1, 16, 2), 256, 0, stream>>>(sc, vc, o_h, pl0);
    }
    oproj_acc<<<dim3(16, 128), 256, 0, stream>>>(o_h, wo, h, x1f);
  }

  ln_stats<<<NTOK, 256, 0, stream>>>(x1f, stats2);
  logits_gemm<<<2048, 256, 0, stream>>>(x1f, stats2, g2, be2, gw, logits);
  routing_kernel<<<32, 256, 0, stream>>>(logits, gval, src, cnt, sums);
  laux_kernel<<<1, 64, 0, stream>>>(sums, cnt, out + (size_t)NTOK * DD);
  copy_x1<<<8192, 256, 0, stream>>>(x1f, out);

  for (int e = 0; e < 8; ++e){
    for (int ccn = 0; ccn < 4; ++ccn){
      int moff = ccn * 1024;
      moe1_gemm<<<dim3(64, 16), 256, 0, stream>>>(x1f, stats2, g2, be2,
          src + e * CAPC + moff, cnt + e, moff, w1 + (size_t)e * (DD * FF), b1 + (size_t)e * FF, hbuf);
      moe2_gemm<<<dim3(16, 16), 256, 0, stream>>>(hbuf, w2 + (size_t)e * (FF * DD),
          b2 + (size_t)e * DD, src + e * CAPC + moff, cnt + e, moff, gval, out);
    }
  }
}